// Round 7
// baseline (81.378 us; speedup 1.0000x reference)
//
#include <hip/hip_runtime.h>

#define BLOCK  256
#define SPT    16     // sources per block (block-uniform -> SGPRs via readfirstlane)
#define NSLICE 256    // target slices = threads per block
#define UN     8      // targets per pipeline stage (8 dwordx4 in flight)

typedef float vfloat2 __attribute__((ext_vector_type(2)));

__device__ __forceinline__ float rfl(float x) {
    return __int_as_float(__builtin_amdgcn_readfirstlane(__float_as_int(x)));
}

// ---- Kernel A: repack targets once into (x,y,z,|t|^2); also zero d_out ----
__global__ __launch_bounds__(256) void prep_kernel(
    const float* __restrict__ tgt, float4* __restrict__ tpre,
    float* __restrict__ out, int M, int Mp, int total)
{
    int i = blockIdx.x * 256 + threadIdx.x;
    if (i == 0) out[0] = 0.f;
    if (i >= total) return;
    int b = i / Mp, m = i - b * Mp;
    float x = 0.f, y = 0.f, z = 0.f, t2 = 1e30f;  // pad sentinel: never wins
    if (m < M) {
        const float* p = tgt + ((size_t)b * M + m) * 3;
        x = p[0]; y = p[1]; z = p[2];
        t2 = fmaf(x, x, fmaf(y, y, z * z));
    }
    tpre[i] = make_float4(x, y, z, t2);
}

// ---- Kernel B: exact 1-NN loss; SGPR sources + register double-buffer ----
// Thread tid scans targets tid+256k (coalesced dwordx4 from L2-resident
// repacked array). 2 targets/step: 3 v_pk_fma_f32 (SGPR src0) + 1 v_min3_f32
// per source = 2 VALU insts/pair. Next UN loads issued BEFORE computing the
// current UN -> >=512 cyc of independent VALU between load issue and use.
__global__ __launch_bounds__(BLOCK) void chamfer_min_kernel(
    const float* __restrict__ src, const float4* __restrict__ tpre,
    float* __restrict__ out, int N, int Mp, int total_src, float scale)
{
    const int tid = threadIdx.x;
    const int sbase = blockIdx.x * SPT;
    const int b = (sbase < total_src) ? (sbase / N) : 0;
    const float* sb = src + (size_t)b * N * 3;
    const float4* tb = tpre + (size_t)b * Mp;

    // block-uniform sources, pre-scaled by -2, pinned to SGPRs
    float nsx[SPT], nsy[SPT], nsz[SPT], mind[SPT];
    unsigned vmask = 0;
#pragma unroll
    for (int u = 0; u < SPT; ++u) {
        int gsi = sbase + u;
        int si  = gsi - b * N;
        bool ok = (gsi < total_src) && (si >= 0) && (si < N);
        if (ok) vmask |= (1u << u);
        float x = 0.f, y = 0.f, z = 0.f;
        if (ok) {
            x = sb[(size_t)si * 3 + 0];
            y = sb[(size_t)si * 3 + 1];
            z = sb[(size_t)si * 3 + 2];
        }
        nsx[u] = rfl(-2.f * x);
        nsy[u] = rfl(-2.f * y);
        nsz[u] = rfl(-2.f * z);
        mind[u] = 1e30f;
    }

    const int TPT = Mp / NSLICE;  // targets/thread; multiple of UN

    float4 tc[UN], tn[UN];
#pragma unroll
    for (int j = 0; j < UN; ++j) tc[j] = tb[(size_t)j * NSLICE + tid];

#pragma unroll 2
    for (int k0 = 0; k0 < TPT; k0 += UN) {
        const bool more = (k0 + UN) < TPT;
        if (more) {
#pragma unroll
            for (int j = 0; j < UN; ++j) {
                tn[j] = tb[(size_t)(k0 + UN + j) * NSLICE + tid];
            }
        }
#pragma unroll
        for (int j = 0; j < UN; j += 2) {
            vfloat2 cx = {tc[j].x, tc[j + 1].x};
            vfloat2 cy = {tc[j].y, tc[j + 1].y};
            vfloat2 cz = {tc[j].z, tc[j + 1].z};
            vfloat2 cw = {tc[j].w, tc[j + 1].w};
#pragma unroll
            for (int u = 0; u < SPT; ++u) {
                vfloat2 sx = {nsx[u], nsx[u]};
                vfloat2 sy = {nsy[u], nsy[u]};
                vfloat2 sz = {nsz[u], nsz[u]};
                vfloat2 d = __builtin_elementwise_fma(sx, cx,
                            __builtin_elementwise_fma(sy, cy,
                            __builtin_elementwise_fma(sz, cz, cw)));
                mind[u] = fminf(mind[u], fminf(d.x, d.y));  // -> v_min3_f32
            }
        }
        if (more) {
#pragma unroll
            for (int j = 0; j < UN; ++j) tc[j] = tn[j];
        }
    }

    // reduce: 64-lane butterfly per source, then across 4 waves via LDS
#pragma unroll
    for (int u = 0; u < SPT; ++u) {
#pragma unroll
        for (int off = 1; off < 64; off <<= 1) {
            mind[u] = fminf(mind[u], __shfl_xor(mind[u], off, 64));
        }
    }

    __shared__ float red[BLOCK / 64][SPT];
    const int lane = tid & 63;
    const int w    = tid >> 6;
    if (lane == 0) {
#pragma unroll
        for (int u = 0; u < SPT; ++u) red[w][u] = mind[u];
    }
    __syncthreads();

    if (tid == 0) {
        float ssum = 0.f;
#pragma unroll
        for (int u = 0; u < SPT; ++u) {
            float mv = red[0][u];
#pragma unroll
            for (int ww = 1; ww < BLOCK / 64; ++ww) mv = fminf(mv, red[ww][u]);
            // recompute |s|^2 from the -2-scaled SGPR copies (tail-only cost)
            float x = -0.5f * nsx[u], y = -0.5f * nsy[u], z = -0.5f * nsz[u];
            float s2 = fmaf(x, x, fmaf(y, y, z * z));
            if (vmask & (1u << u)) ssum += s2 + mv;
        }
        atomicAdd(out, ssum * scale);
    }
}

extern "C" void kernel_launch(void* const* d_in, const int* in_sizes, int n_in,
                              void* d_out, int out_size, void* d_ws, size_t ws_size,
                              hipStream_t stream) {
    const float* src = (const float*)d_in[0];  // [B, N, 3] fp32
    const float* tgt = (const float*)d_in[1];  // [B, M, 3] fp32
    float* out = (float*)d_out;                // scalar fp32

    const int B = 2;
    const int N = in_sizes[0] / (B * 3);
    const int M = in_sizes[1] / (B * 3);
    const int total_src = B * N;

    // pad targets-per-batch to a multiple of NSLICE*UN for an exact hot loop
    const int step = NSLICE * UN;
    const int Mp = ((M + step - 1) / step) * step;
    float4* tpre = (float4*)d_ws;  // B*Mp*16 bytes << ws_size

    const int prep_total = B * Mp;
    prep_kernel<<<(prep_total + 255) / 256, 256, 0, stream>>>(
        tgt, tpre, out, M, Mp, prep_total);

    const int grid = (total_src + SPT - 1) / SPT;  // 1024 blocks
    chamfer_min_kernel<<<grid, BLOCK, 0, stream>>>(
        src, tpre, out, N, Mp, total_src,
        1.0f / (3.0f * (float)N * (float)B));
}

// Round 8
// 73.214 us; speedup vs baseline: 1.1115x; 1.1115x over previous
//
#include <hip/hip_runtime.h>

#define BLOCK  256
#define TSPLIT 32    // target chunks (partial-min buffer depth)

typedef float vfloat2 __attribute__((ext_vector_type(2)));

// ---- Kernel A: repack targets to SoA (TX|TY|TZ|TW), pad with sentinels,
//      and zero d_out (replaces a memset node). ----
__global__ __launch_bounds__(256) void prep_kernel(
    const float* __restrict__ tgt, float* __restrict__ soa,
    float* __restrict__ out, int M, int Mp, int BMp)
{
    int i = blockIdx.x * 256 + threadIdx.x;
    if (i == 0) out[0] = 0.f;
    if (i >= BMp) return;
    int b = i / Mp, m = i - b * Mp;
    float x = 0.f, y = 0.f, z = 0.f, w = 1e30f;  // pad: never wins the min
    if (m < M) {
        const float* p = tgt + ((size_t)b * M + m) * 3;
        x = p[0]; y = p[1]; z = p[2];
        w = fmaf(x, x, fmaf(y, y, z * z));
    }
    soa[i]           = x;
    soa[BMp + i]     = y;
    soa[2 * BMp + i] = z;
    soa[3 * BMp + i] = w;
}

// ---- Kernel B (pass 1): one SOURCE PER LANE; block scans one target chunk.
// Target data is wave-uniform SoA float2 -> scalar loads (SMEM pipe), pairs
// land in adjacent SGPRs -> v_pk_fma with zero packing movs. Per 2 targets:
// pk_mul + 2 pk_fma + pk_add + v_min3 = 2.5 VALU insts/pair. mind is one
// VGPR per lane; NO cross-lane reduction, NO LDS, NO barriers.
__global__ __launch_bounds__(BLOCK, 8) void nn_chunk_kernel(
    const float* __restrict__ src, const float* __restrict__ soa,
    float* __restrict__ partial, int N, int Mp, int BMp, int SGB, int BN)
{
    const int tid = threadIdx.x;
    const int c   = blockIdx.x % TSPLIT;         // target chunk  (uniform)
    const int sgg = blockIdx.x / TSPLIT;
    const int b   = sgg / SGB;                   // batch         (uniform)
    const int sgl = sgg - b * SGB;
    const int si  = sgl * BLOCK + tid;           // source within batch

    // per-lane source, pre-scaled by -2, splatted to pk pairs
    float x = 0.f, y = 0.f, z = 0.f;
    if (si < N) {
        const float* p = src + ((size_t)b * N + si) * 3;
        x = p[0]; y = p[1]; z = p[2];
    }
    const vfloat2 nsx = {-2.f * x, -2.f * x};
    const vfloat2 nsy = {-2.f * y, -2.f * y};
    const vfloat2 nsz = {-2.f * z, -2.f * z};
    float mind = 1e30f;

    // wave-uniform target pointers (float2 views of the SoA arrays)
    const int CHT = Mp / TSPLIT;                 // targets per chunk (even)
    const int f2b = (b * Mp + c * CHT) >> 1;     // uniform float2 index
    const vfloat2* __restrict__ TX = (const vfloat2*)soa;
    const vfloat2* __restrict__ TY = (const vfloat2*)(soa + BMp);
    const vfloat2* __restrict__ TZ = (const vfloat2*)(soa + 2 * BMp);
    const vfloat2* __restrict__ TW = (const vfloat2*)(soa + 3 * BMp);

#pragma unroll 8
    for (int k = 0; k < CHT / 2; ++k) {
        vfloat2 x01 = TX[f2b + k];
        vfloat2 y01 = TY[f2b + k];
        vfloat2 z01 = TZ[f2b + k];
        vfloat2 w01 = TW[f2b + k];
        vfloat2 e = x01 * nsx;                       // v_pk_mul_f32
        e = __builtin_elementwise_fma(y01, nsy, e);  // v_pk_fma_f32
        e = __builtin_elementwise_fma(z01, nsz, e);  // v_pk_fma_f32
        vfloat2 d = e + w01;                         // v_pk_add_f32
        mind = fminf(mind, fminf(d.x, d.y));         // v_min3_f32
    }

    if (si < N) {
        partial[(size_t)c * BN + (size_t)b * N + si] = mind;  // coalesced
    }
}

// ---- Kernel C (pass 2): per source min over chunks, +|s|^2, sum, atomic ----
__global__ __launch_bounds__(BLOCK) void reduce_kernel(
    const float* __restrict__ src, const float* __restrict__ partial,
    float* __restrict__ out, int BN, float scale)
{
    const int i = blockIdx.x * BLOCK + threadIdx.x;
    float v = 0.f;
    if (i < BN) {
        float m0 = 1e30f, m1 = 1e30f, m2 = 1e30f, m3 = 1e30f;
#pragma unroll
        for (int c = 0; c < TSPLIT; c += 4) {
            m0 = fminf(m0, partial[(size_t)(c + 0) * BN + i]);
            m1 = fminf(m1, partial[(size_t)(c + 1) * BN + i]);
            m2 = fminf(m2, partial[(size_t)(c + 2) * BN + i]);
            m3 = fminf(m3, partial[(size_t)(c + 3) * BN + i]);
        }
        float x = src[(size_t)i * 3 + 0];
        float y = src[(size_t)i * 3 + 1];
        float z = src[(size_t)i * 3 + 2];
        v = fmaf(x, x, fmaf(y, y, z * z))
          + fminf(fminf(m0, m1), fminf(m2, m3));     // = min ||s-t||^2
    }

#pragma unroll
    for (int off = 32; off > 0; off >>= 1) v += __shfl_xor(v, off, 64);

    __shared__ float wsum[BLOCK / 64];
    const int lane = threadIdx.x & 63;
    const int w    = threadIdx.x >> 6;
    if (lane == 0) wsum[w] = v;
    __syncthreads();
    if (threadIdx.x == 0) {
        float s = 0.f;
#pragma unroll
        for (int k = 0; k < BLOCK / 64; ++k) s += wsum[k];
        atomicAdd(out, s * scale);
    }
}

extern "C" void kernel_launch(void* const* d_in, const int* in_sizes, int n_in,
                              void* d_out, int out_size, void* d_ws, size_t ws_size,
                              hipStream_t stream) {
    const float* src = (const float*)d_in[0];  // [B, N, 3] fp32
    const float* tgt = (const float*)d_in[1];  // [B, M, 3] fp32
    float* out = (float*)d_out;                // scalar fp32

    const int B = 2;
    const int N = in_sizes[0] / (B * 3);
    const int M = in_sizes[1] / (B * 3);
    const int BN = B * N;

    // pad targets-per-batch so chunks are a multiple of 2*unroll targets
    const int step = TSPLIT * 16;
    const int Mp  = ((M + step - 1) / step) * step;   // 8192 stays 8192
    const int BMp = B * Mp;

    float* soa     = (float*)d_ws;                    // 4*BMp floats (SoA)
    float* partial = soa + 4 * (size_t)BMp;           // TSPLIT*BN floats

    prep_kernel<<<(BMp + 255) / 256, 256, 0, stream>>>(tgt, soa, out, M, Mp, BMp);

    const int SGB = (N + BLOCK - 1) / BLOCK;          // source groups / batch
    const int grid1 = B * SGB * TSPLIT;               // 2048 blocks
    nn_chunk_kernel<<<grid1, BLOCK, 0, stream>>>(src, soa, partial,
                                                 N, Mp, BMp, SGB, BN);

    reduce_kernel<<<(BN + BLOCK - 1) / BLOCK, BLOCK, 0, stream>>>(
        src, partial, out, BN, 1.0f / (3.0f * (float)N * (float)B));
}